// Round 12
// baseline (296.720 us; speedup 1.0000x reference)
//
#include <hip/hip_runtime.h>

// AlphaCompositionShader: B=4,H=512,W=512,K=8.  P = B*H*W = 1048576 pixels.
// R8: R7 (97.4us best) with 2x fat threads over ADJACENT streams: each wave
// handles two consecutive 64-fragment blocks; lane processes fragments
// f0 = 128*wave + lane and f1 = f0 + 64 (1 KiB apart -> same DRAM page, no
// power-of-two-MiB stride aliasing, unlike R5/R6 whose 8 MiB strides
// confounded the MLP test). All 6 loads issue up front: set0 computes at
// vmcnt(3), set1 at vmcnt(0) -> 2-stage pipeline in straight-line code,
// 2x per-wave in-flight read bytes, half the wave launch/retire count.
// Evidence this axis matters: same-capture fillBufferAligned hits 6.5 TB/s
// at 9.9% occupancy (deep per-wave pipelining, not occupancy, drives BW).
// Per-set compute identical to R7: width-8 DPP scans, nibble-packed labels,
// 4 ds_bpermute per set (human gather), plain stores (R7 A/B: nt cost ~3us).
// Output layout identical to prior rounds:
//   [0,4P) image | [4P,5P) depth | [5P,6P) label | [6P,38P) human

#define BKG_DEPTH 100.0f
#define KD 8

typedef float f32x4 __attribute__((ext_vector_type(4)));

#define QP_XOR1 0xB1              // quad_perm [1,0,3,2]
#define QP_XOR2 0x4E              // quad_perm [2,3,0,1]
#define ROW_SHL(n) (0x100 | (n))  // dst lane r <- src lane r+n (within 16-row)
#define ROW_SHR(n) (0x110 | (n))  // dst lane r <- src lane r-n (within 16-row)

template <int CTRL>
__device__ __forceinline__ float dppf(float x) {
    return __int_as_float(__builtin_amdgcn_update_dpp(
        0, __float_as_int(x), CTRL, 0xF, 0xF, true));
}
template <int CTRL>
__device__ __forceinline__ int dppi(int x) {
    return __builtin_amdgcn_update_dpp(0, x, CTRL, 0xF, 0xF, true);
}

__device__ __forceinline__ void composite_set(
    const float4 c, const float z, const int lbl,
    const int pix, const int tid, const int kk, const int lane,
    const float bg0, const float bg1, const float bg2,
    float* __restrict__ out, const int P)
{
    const float alpha = c.w;
    const bool  valid = !(z < 0.0f);

    // inclusive prefix product of (1-a) via DPP scan (3 steps)
    float incl = 1.0f - alpha;
    { const float u = dppf<ROW_SHR(1)>(incl); incl = (kk >= 1) ? incl * u : incl; }
    { const float u = dppf<ROW_SHR(2)>(incl); incl = (kk >= 2) ? incl * u : incl; }
    { const float u = dppf<ROW_SHR(4)>(incl); incl = (kk >= 4) ? incl * u : incl; }
    float pre = dppf<ROW_SHR(1)>(incl); pre = (kk == 0) ? 1.0f : pre;  // exclusive
    const float T = dppf<ROW_SHL(7)>(incl);   // full product, valid in lane kk==0
    const float w = alpha * pre;

    // rgb weighted sums + max alpha (totals valid in kk<4 after combine)
    float sr = c.x * w, sg = c.y * w, sb = c.z * w, am = alpha;
    sr += dppf<QP_XOR1>(sr); sg += dppf<QP_XOR1>(sg); sb += dppf<QP_XOR1>(sb);
    am = fmaxf(am, dppf<QP_XOR1>(am));
    sr += dppf<QP_XOR2>(sr); sg += dppf<QP_XOR2>(sg); sb += dppf<QP_XOR2>(sb);
    am = fmaxf(am, dppf<QP_XOR2>(am));
    sr += dppf<ROW_SHL(4)>(sr); sg += dppf<ROW_SHL(4)>(sg); sb += dppf<ROW_SHL(4)>(sb);
    am = fmaxf(am, dppf<ROW_SHL(4)>(am));    // fmax(x,0) harmless in unused lanes

    // depth: layers with z>0 participate, others transparent
    const float a2 = (z > 0.0f) ? alpha : 0.0f;
    float incl2 = 1.0f - a2;
    { const float u = dppf<ROW_SHR(1)>(incl2); incl2 = (kk >= 1) ? incl2 * u : incl2; }
    { const float u = dppf<ROW_SHR(2)>(incl2); incl2 = (kk >= 2) ? incl2 * u : incl2; }
    { const float u = dppf<ROW_SHR(4)>(incl2); incl2 = (kk >= 4) ? incl2 * u : incl2; }
    float pre2 = dppf<ROW_SHR(1)>(incl2); pre2 = (kk == 0) ? 1.0f : pre2;
    const float T2 = dppf<ROW_SHL(6)>(incl2); // full product, valid in lane kk==1
    float sd = z * (a2 * pre2);               // 0 when a2==0
    sd += dppf<QP_XOR1>(sd);
    sd += dppf<QP_XOR2>(sd);
    sd += dppf<ROW_SHL(4)>(sd);               // total valid in kk<4
    const float outD = fmaf(BKG_DEPTH, T2, sd);

    // pack all 8 labels as nibbles into one word (every lane gets full word)
    int pw = (valid ? lbl : 0xF) << (4 * kk);
    pw |= dppi<QP_XOR1>(pw);
    pw |= dppi<QP_XOR2>(pw);
    {
        const int lo = dppi<ROW_SHL(4)>(pw);  // other quad, valid for kk<4
        const int hi = dppi<ROW_SHR(4)>(pw);  // other quad, valid for kk>=4
        pw |= (kk & 4) ? hi : lo;
    }

    // composite label: min k with (valid && alpha>0.5), else -1
    const unsigned long long bal = __ballot(valid && (alpha > 0.5f));
    const unsigned grpByte = (unsigned)((bal >> (lane & ~7)) & 0xFFull);
    const int jlab = grpByte ? (__ffs(grpByte) - 1) : 0;
    const float labv = grpByte ? (float)((pw >> (4 * jlab)) & 0xF) : -1.0f;

    // human image for label n = kk: front-most fragment with nibble==kk
    int jm = 8;                                // sentinel: no hit
    #pragma unroll
    for (int j = 7; j >= 0; --j)
        jm = (((pw >> (4 * j)) & 0xF) == kk) ? j : jm;
    const bool hit = (jm < 8);
    const int src = hit ? jm : 0;
    float gx = __shfl(c.x, src, 8);            // the only 4 ds_bpermute ops
    float gy = __shfl(c.y, src, 8);
    float gz = __shfl(c.z, src, 8);
    float gw = __shfl(c.w, src, 8);
    gx = hit ? gx : 0.0f;  gy = hit ? gy : 0.0f;
    gz = hit ? gz : 0.0f;  gw = hit ? gw : 0.0f;
    const float ia = 1.0f - gw;
    const f32x4 hv = { fmaf(gx, gw, bg0 * ia),
                       fmaf(gy, gw, bg1 * ia),
                       fmaf(gz, gw, bg2 * ia),
                       gw };

    // stores: plain (R7 A/B result)
    ((f32x4*)(out + (size_t)6 * P))[tid] = hv;
    if (kk == 0) {
        const f32x4 img = { fmaf(bg0, T, sr), fmaf(bg1, T, sg), fmaf(bg2, T, sb), am };
        ((f32x4*)out)[pix] = img;
    }
    if (kk == 1) out[(size_t)4 * P + pix] = outD;
    if (kk == 2) out[(size_t)5 * P + pix] = labv;
}

__global__ __launch_bounds__(256) void alpha_comp_pair(
    const float4* __restrict__ pc,   // P*8 rgba fragments
    const float*  __restrict__ zb,   // P*8 z
    const int*    __restrict__ lb,   // P*8 labels (0..7)
    const float*  __restrict__ bg,   // 3 floats
    float* __restrict__ out,
    int P)
{
    const int t = blockIdx.x * blockDim.x + threadIdx.x;    // half-fragment idx
    const int f0 = t + (t & ~63);                           // = 128*wave + lane
    const int f1 = f0 + 64;                                 // adjacent block
    if (f1 >= P * KD + 64) return;                          // grid exact; safety

    const int kk   = f0 & 7;                                // same for f1 (64%8==0)
    const int lane = threadIdx.x & 63;
    const float bg0 = bg[0], bg1 = bg[1], bg2 = bg[2];

    // ---- all 6 loads issue up front (set0 ready at vmcnt(3), set1 at vmcnt(0))
    const float4 c0 = pc[f0];
    const float  z0 = zb[f0];
    const int    l0 = lb[f0];
    const float4 c1 = pc[f1];
    const float  z1 = zb[f1];
    const int    l1 = lb[f1];

    composite_set(c0, z0, l0, f0 >> 3, f0, kk, lane, bg0, bg1, bg2, out, P);
    composite_set(c1, z1, l1, f1 >> 3, f1, kk, lane, bg0, bg1, bg2, out, P);
}

extern "C" void kernel_launch(void* const* d_in, const int* in_sizes, int n_in,
                              void* d_out, int out_size, void* d_ws, size_t ws_size,
                              hipStream_t stream) {
    const float4* pc = (const float4*)d_in[0];   // pixel_colors (B,H,W,K,4) f32
    const float*  zb = (const float*)d_in[1];    // zbuf (B,H,W,K) f32
    const int*    lb = (const int*)d_in[2];      // pixel_labels (B,H,W,K) i32
    const float*  bg = (const float*)d_in[3];    // background_color (3,) f32
    float* out = (float*)d_out;

    const int P = in_sizes[1] / KD;              // B*H*W = 1048576
    const int total = P * KD;                    // fragments
    const int nthreads = total / 2;              // each thread: 2 fragments
    const int block = 256;
    const int grid = (nthreads + block - 1) / block;  // 16384 blocks
    alpha_comp_pair<<<grid, block, 0, stream>>>(pc, zb, lb, bg, out, P);
}